// Round 11
// baseline (102.843 us; speedup 1.0000x reference)
//
#include <hip/hip_runtime.h>
#include <hip/hip_bf16.h>
#include <cmath>

typedef __attribute__((ext_vector_type(8))) short short8;
typedef __attribute__((ext_vector_type(4))) float f32x4;

#define EPS_F 1e-7f
#define NEG_DIAG_F -10.0f
#define NPART 256    // per-row max slots: 128 direct (bx) + 128 transposed (by)

__device__ __forceinline__ f32x4 mfma16(short8 a, short8 b, f32x4 c) {
    return __builtin_amdgcn_mfma_f32_16x16x32_bf16(a, b, c, 0, 0, 0);
}

// ---------------------------------------------------------------------------
// Kernel 1: row L2-normalize feat_k / feat_g (f32), cast to bf16; zero P.
// ---------------------------------------------------------------------------
__global__ void norm_cast_kernel(const float* __restrict__ fk, const float* __restrict__ fg,
                                 __hip_bfloat16* __restrict__ fkb, __hip_bfloat16* __restrict__ fgb,
                                 float* __restrict__ P, int N, int D) {
    int n = blockIdx.x;
    int t = threadIdx.x;
    float xk = fk[(size_t)n * D + t];
    float xg = fg[(size_t)n * D + t];
    float sk = xk * xk, sg = xg * xg;
#pragma unroll
    for (int off = 32; off > 0; off >>= 1) {
        sk += __shfl_xor(sk, off, 64);
        sg += __shfl_xor(sg, off, 64);
    }
    __shared__ float lsk[4], lsg[4];
    int w = t >> 6, l = t & 63;
    if (l == 0) { lsk[w] = sk; lsg[w] = sg; }
    __syncthreads();
    sk = lsk[0] + lsk[1] + lsk[2] + lsk[3];
    sg = lsg[0] + lsg[1] + lsg[2] + lsg[3];
    float rkv = 1.0f / (sqrtf(sk) + EPS_F);
    float rgv = 1.0f / (sqrtf(sg) + EPS_F);
    fkb[(size_t)n * D + t] = __float2bfloat16(xk * rkv);
    fgb[(size_t)n * D + t] = __float2bfloat16(xg * rgv);
    P[(size_t)n * NPART + t] = 0.0f;
}

// ---------------------------------------------------------------------------
// Kernel 2: ONE WAVE per 32x32 upper-triangle tile; no __syncthreads at all.
// Fragments from global (L2-resident), 2-deep named register pipeline.
// Per-wave LDS bounce (stride 36 + granule-XOR) for coalesced stores of the
// tile and its transpose.  Row/col maxes to unique P slots (no atomics).
// ---------------------------------------------------------------------------
#define LOADS(p0, p1, p2, p3, p4, p5, p6, p7, KK)              \
    p0 = *(const short8*)(Ak + (KK) * 64);                     \
    p1 = *(const short8*)(Ak + 8192 + (KK) * 64);              \
    p2 = *(const short8*)(Ag + (KK) * 64);                     \
    p3 = *(const short8*)(Ag + 8192 + (KK) * 64);              \
    p4 = *(const short8*)(Bk + (KK) * 64);                     \
    p5 = *(const short8*)(Bk + 8192 + (KK) * 64);              \
    p6 = *(const short8*)(Bg + (KK) * 64);                     \
    p7 = *(const short8*)(Bg + 8192 + (KK) * 64);

#define MFMAS(p0, p1, p2, p3, p4, p5, p6, p7)                  \
    k00 = mfma16(p0, p4, k00);  k01 = mfma16(p0, p5, k01);     \
    k10 = mfma16(p1, p4, k10);  k11 = mfma16(p1, p5, k11);     \
    g00 = mfma16(p2, p6, g00);  g01 = mfma16(p2, p7, g01);     \
    g10 = mfma16(p3, p6, g10);  g11 = mfma16(p3, p7, g11);

__global__ __launch_bounds__(256, 4) void gram_wt_kernel(
    const __hip_bfloat16* __restrict__ fkb, const __hip_bfloat16* __restrict__ fgb,
    float* __restrict__ out, float* __restrict__ P, int N) {

    __shared__ __align__(16) float bncs[4 * 32 * 36];   // 18432 B, per-wave [32][36]
    int t = threadIdx.x;
    int w = t >> 6, l = t & 63;
    int lr = l & 15, lg = l >> 4;
    float* bw = bncs + w * (32 * 36);

    int T = blockIdx.x * 4 + w;             // tile id 0..8255
    // decode upper-tri (by<=bx) over 128 row-tiles: cum(r) = r*(257-r)/2
    float ff = (257.0f - sqrtf(66049.0f - 8.0f * (float)T)) * 0.5f;
    int by = (int)ff;
    while ((by + 1) * (257 - (by + 1)) <= 2 * T) ++by;
    while (by * (257 - by) > 2 * T) --by;
    int bx = by + (T - (by * (257 - by)) / 2);
    int r0 = by * 32, c0 = bx * 32;

    // per-lane fragment base pointers (row-major, 512 B/row, lane row = +lr)
    const char* Ak = (const char*)fkb + (size_t)(r0 + lr) * 512 + lg * 16;
    const char* Ag = (const char*)fgb + (size_t)(r0 + lr) * 512 + lg * 16;
    const char* Bk = (const char*)fkb + (size_t)(c0 + lr) * 512 + lg * 16;
    const char* Bg = (const char*)fgb + (size_t)(c0 + lr) * 512 + lg * 16;

    f32x4 k00, k01, k10, k11, g00, g01, g10, g11;
    f32x4 zero = {0.f, 0.f, 0.f, 0.f};
    k00 = k01 = k10 = k11 = g00 = g01 = g10 = g11 = zero;

    short8 Aa0, Aa1, Aa2, Aa3, Aa4, Aa5, Aa6, Aa7;   // set A
    short8 Bb0, Bb1, Bb2, Bb3, Bb4, Bb5, Bb6, Bb7;   // set B

    LOADS(Aa0, Aa1, Aa2, Aa3, Aa4, Aa5, Aa6, Aa7, 0)
#pragma unroll
    for (int it = 0; it < 4; ++it) {
        const int k0 = 2 * it;
        LOADS(Bb0, Bb1, Bb2, Bb3, Bb4, Bb5, Bb6, Bb7, k0 + 1)
        MFMAS(Aa0, Aa1, Aa2, Aa3, Aa4, Aa5, Aa6, Aa7)
        if (k0 + 2 < 8) { LOADS(Aa0, Aa1, Aa2, Aa3, Aa4, Aa5, Aa6, Aa7, k0 + 2) }
        MFMAS(Bb0, Bb1, Bb2, Bb3, Bb4, Bb5, Bb6, Bb7)
    }

    // --- ratio + diag ------------------------------------------------------
    f32x4 sv[2][2];
    sv[0][0] = k00; sv[0][1] = k01; sv[1][0] = k10; sv[1][1] = k11;
    f32x4 gv[2][2];
    gv[0][0] = g00; gv[0][1] = g01; gv[1][0] = g10; gv[1][1] = g11;
#pragma unroll
    for (int m = 0; m < 2; ++m)
#pragma unroll
        for (int n = 0; n < 2; ++n)
#pragma unroll
            for (int j = 0; j < 4; ++j) {
                float s = (sv[m][n][j] + 1.0f + EPS_F) *
                          __builtin_amdgcn_rcpf(gv[m][n][j] + 1.0f + EPS_F);
                int lrow = m * 16 + lg * 4 + j;      // C/D: row=(l>>4)*4+reg
                int lcol = n * 16 + lr;              // col=l&15
                if (r0 + lrow == c0 + lcol) s = NEG_DIAG_F;
                sv[m][n][j] = s;
            }

    // --- row maxes -> P[row][bx] -------------------------------------------
#pragma unroll
    for (int m = 0; m < 2; ++m)
#pragma unroll
        for (int j = 0; j < 4; ++j) {
            float pm = fmaxf(sv[m][0][j], sv[m][1][j]);
            pm = fmaxf(pm, __shfl_xor(pm, 1, 64));
            pm = fmaxf(pm, __shfl_xor(pm, 2, 64));
            pm = fmaxf(pm, __shfl_xor(pm, 4, 64));
            pm = fmaxf(pm, __shfl_xor(pm, 8, 64));
            if (lr == 0)
                P[(size_t)(r0 + m * 16 + lg * 4 + j) * NPART + bx] = pm;
        }
    // --- col maxes -> P[col][128+by] (off-diag only; diag is symmetric) ----
    if (bx > by) {
#pragma unroll
        for (int n = 0; n < 2; ++n) {
            float cm = fmaxf(fmaxf(sv[0][n][0], sv[0][n][1]), fmaxf(sv[0][n][2], sv[0][n][3]));
            cm = fmaxf(cm, fmaxf(fmaxf(sv[1][n][0], sv[1][n][1]), fmaxf(sv[1][n][2], sv[1][n][3])));
            cm = fmaxf(cm, __shfl_xor(cm, 16, 64));
            cm = fmaxf(cm, __shfl_xor(cm, 32, 64));
            if (lg == 0)
                P[(size_t)(c0 + n * 16 + lr) * NPART + 128 + by] = cm;
        }
    }

    // --- direct tile: per-wave bounce [32][36], coalesced 128B row stores --
#pragma unroll
    for (int m = 0; m < 2; ++m)
#pragma unroll
        for (int n = 0; n < 2; ++n)
#pragma unroll
            for (int j = 0; j < 4; ++j)
                bw[(m * 16 + lg * 4 + j) * 36 + n * 16 + lr] = sv[m][n][j];
    asm volatile("s_waitcnt lgkmcnt(0)" ::: "memory");
#pragma unroll
    for (int i = 0; i < 4; ++i) {
        int rr = i * 8 + (l >> 3);
        f32x4 v = *(const f32x4*)&bw[rr * 36 + (l & 7) * 4];
        *(f32x4*)(out + (size_t)(r0 + rr) * N + c0 + (l & 7) * 4) = v;
    }

    // --- transposed tile (granule-XOR swizzle to break 8-way writes) -------
    if (bx > by) {
#pragma unroll
        for (int m = 0; m < 2; ++m)
#pragma unroll
            for (int n = 0; n < 2; ++n) {
                int prow = n * 16 + lr;
                int pg = ((m * 4 + lg) ^ (lr & 7)) * 4;
#pragma unroll
                for (int j = 0; j < 4; ++j)
                    bw[prow * 36 + pg + j] = sv[m][n][j];
            }
        asm volatile("s_waitcnt lgkmcnt(0)" ::: "memory");
#pragma unroll
        for (int i = 0; i < 4; ++i) {
            int rr = i * 8 + (l >> 3);
            int phys = ((l & 7) ^ (rr & 7)) * 4;
            f32x4 v = *(const f32x4*)&bw[rr * 36 + phys];
            *(f32x4*)(out + (size_t)(c0 + rr) * N + r0 + (l & 7) * 4) = v;
        }
    }
}

// ---------------------------------------------------------------------------
// Kernel 3: one block per row: m = max_j P[row][j]; out = exp(out - m).
// ---------------------------------------------------------------------------
__global__ void finalize_kernel(float* __restrict__ out, const float* __restrict__ P, int N) {
    int row = blockIdx.x;
    int t = threadIdx.x;            // 256
    int l = t & 63;
    const float* pr = P + (size_t)row * NPART;
    float m = fmaxf(fmaxf(pr[l], pr[l + 64]), fmaxf(pr[l + 128], pr[l + 192]));
#pragma unroll
    for (int off = 1; off < 64; off <<= 1)
        m = fmaxf(m, __shfl_xor(m, off, 64));
    float4* o4 = (float4*)(out + (size_t)row * N);
    int n4 = N >> 2;
    for (int i = t; i < n4; i += 256) {
        float4 v = o4[i];
        v.x = __expf(v.x - m);
        v.y = __expf(v.y - m);
        v.z = __expf(v.z - m);
        v.w = __expf(v.w - m);
        o4[i] = v;
    }
}

// ---------------------------------------------------------------------------
extern "C" void kernel_launch(void* const* d_in, const int* in_sizes, int n_in,
                              void* d_out, int out_size, void* d_ws, size_t ws_size,
                              hipStream_t stream) {
    const float* fk = (const float*)d_in[1];
    const float* fg = (const float*)d_in[2];
    float* out = (float*)d_out;

    int N = (int)llround(sqrt((double)out_size));   // 4096
    int D = in_sizes[1] / N;                        // 256

    char* ws = (char*)d_ws;
    float* P = (float*)ws;                                          // N*256*4 = 4 MB
    __hip_bfloat16* fkb = (__hip_bfloat16*)(ws + (size_t)N * NPART * 4);
    __hip_bfloat16* fgb = fkb + (size_t)N * D;

    norm_cast_kernel<<<N, D, 0, stream>>>(fk, fg, fkb, fgb, P, N, D);

    gram_wt_kernel<<<2064, 256, 0, stream>>>(fkb, fgb, out, P, N);

    finalize_kernel<<<N, 256, 0, stream>>>(out, P, N);
}

// Round 12
// 67.497 us; speedup vs baseline: 1.5237x; 1.5237x over previous
//
#include <hip/hip_runtime.h>
#include <hip/hip_bf16.h>
#include <cmath>

typedef __attribute__((ext_vector_type(8))) short short8;
typedef __attribute__((ext_vector_type(4))) float f32x4;
typedef __attribute__((ext_vector_type(4))) _Float16 h16x4;
typedef __attribute__((ext_vector_type(8))) _Float16 h16x8;

#define EPS_F 1e-7f
#define NEG_DIAG_F -10.0f
#define NPART 128           // per-row max slots: 64 direct (bx) + 64 transposed (by)

__device__ __forceinline__ void gload_lds16(const void* gptr, void* ldsptr) {
    __builtin_amdgcn_global_load_lds(
        (const __attribute__((address_space(1))) unsigned int*)gptr,
        (__attribute__((address_space(3))) unsigned int*)ldsptr,
        16, 0, 0);
}

// ---------------------------------------------------------------------------
// Kernel 1: row L2-normalize feat_k / feat_g (f32), cast to bf16; zero P.
// ---------------------------------------------------------------------------
__global__ void norm_cast_kernel(const float* __restrict__ fk, const float* __restrict__ fg,
                                 __hip_bfloat16* __restrict__ fkb, __hip_bfloat16* __restrict__ fgb,
                                 float* __restrict__ P, int N, int D) {
    int n = blockIdx.x;
    int t = threadIdx.x;
    float xk = fk[(size_t)n * D + t];
    float xg = fg[(size_t)n * D + t];
    float sk = xk * xk, sg = xg * xg;
#pragma unroll
    for (int off = 32; off > 0; off >>= 1) {
        sk += __shfl_xor(sk, off, 64);
        sg += __shfl_xor(sg, off, 64);
    }
    __shared__ float lsk[4], lsg[4];
    int w = t >> 6, l = t & 63;
    if (l == 0) { lsk[w] = sk; lsg[w] = sg; }
    __syncthreads();
    sk = lsk[0] + lsk[1] + lsk[2] + lsk[3];
    sg = lsg[0] + lsg[1] + lsg[2] + lsg[3];
    float rkv = 1.0f / (sqrtf(sk) + EPS_F);
    float rgv = 1.0f / (sqrtf(sg) + EPS_F);
    fkb[(size_t)n * D + t] = __float2bfloat16(xk * rkv);
    fgb[(size_t)n * D + t] = __float2bfloat16(xg * rgv);
    if (t < NPART) P[(size_t)n * NPART + t] = 0.0f;
}

// ---------------------------------------------------------------------------
// Kernel 2 (R7 structure): 64x64-tile upper-triangle dual Gram, 4 waves,
// BK=32, single-buffered.  F16=1: quantize s to fp16, store to fp16 sbuf
// (half the write traffic); F16=0: store f32 directly to out (R7 fallback).
// ---------------------------------------------------------------------------
template <int F16>
__global__ __launch_bounds__(256, 5) void gram64_kernel(
    const __hip_bfloat16* __restrict__ fkb, const __hip_bfloat16* __restrict__ fgb,
    void* __restrict__ sout, float* __restrict__ P, int N, int D) {

    __shared__ __align__(16) char smem[17408 + 512];   // staging(16K) ∪ bounce [64][66]f32; lmax
    float* bnc = (float*)smem;
    int* lmax = (int*)(smem + 17408);                   // [0..63] row, [64..127] col

    int bx = blockIdx.x, by = blockIdx.y;
    if (bx < by) return;
    int r0 = by * 64, c0 = bx * 64;

    int t = threadIdx.x;
    int w = t >> 6, l = t & 63;
    int wr = w >> 1, wc = w & 1;    // 2x2 wave grid; wave tile = 32 rows x 32 cols
    int lr = l & 15, lg = l >> 4;

    if (t < NPART) lmax[t] = 0;

    int aoff[2], boff[2];
#pragma unroll
    for (int m = 0; m < 2; ++m) {
        int row = wr * 32 + m * 16 + lr;
        aoff[m] = row * 64 + ((lg ^ ((row >> 1) & 3)) << 4);
    }
#pragma unroll
    for (int n = 0; n < 2; ++n) {
        int row = wc * 32 + n * 16 + lr;
        boff[n] = row * 64 + ((lg ^ ((row >> 1) & 3)) << 4);
    }

    int srow = t >> 2;
    int scsw = ((t & 3) ^ ((srow >> 1) & 3)) << 4;
    const size_t rowbytes = (size_t)D * 2;
    size_t gA = (size_t)(r0 + srow) * rowbytes + scsw;
    size_t gB = (size_t)(c0 + srow) * rowbytes + scsw;
    int sdst = w << 10;

    f32x4 acck[2][2], accg[2][2];
    f32x4 zero = {0.f, 0.f, 0.f, 0.f};
#pragma unroll
    for (int m = 0; m < 2; ++m)
#pragma unroll
        for (int n = 0; n < 2; ++n) { acck[m][n] = zero; accg[m][n] = zero; }

    for (int k0 = 0; k0 < D; k0 += 32) {
        size_t kb = (size_t)k0 * 2;
        gload_lds16((const char*)fkb + gA + kb, smem + sdst);
        gload_lds16((const char*)fgb + gA + kb, smem + 4096 + sdst);
        gload_lds16((const char*)fkb + gB + kb, smem + 8192 + sdst);
        gload_lds16((const char*)fgb + gB + kb, smem + 12288 + sdst);
        __syncthreads();

        short8 ak[2], ag[2], bk[2], bg[2];
#pragma unroll
        for (int m = 0; m < 2; ++m) {
            ak[m] = *(const short8*)(smem + aoff[m]);
            ag[m] = *(const short8*)(smem + 4096 + aoff[m]);
        }
#pragma unroll
        for (int n = 0; n < 2; ++n) {
            bk[n] = *(const short8*)(smem + 8192 + boff[n]);
            bg[n] = *(const short8*)(smem + 12288 + boff[n]);
        }
        __builtin_amdgcn_s_setprio(1);
#pragma unroll
        for (int m = 0; m < 2; ++m)
#pragma unroll
            for (int n = 0; n < 2; ++n) {
                acck[m][n] = __builtin_amdgcn_mfma_f32_16x16x32_bf16(ak[m], bk[n], acck[m][n], 0, 0, 0);
                accg[m][n] = __builtin_amdgcn_mfma_f32_16x16x32_bf16(ag[m], bg[n], accg[m][n], 0, 0, 0);
            }
        __builtin_amdgcn_s_setprio(0);
        __syncthreads();
    }

    // --- epilogue: ratio + diag (+fp16 quantize), in place -----------------
#pragma unroll
    for (int m = 0; m < 2; ++m)
#pragma unroll
        for (int j = 0; j < 4; ++j) {
            int lrow = wr * 32 + m * 16 + lg * 4 + j;
#pragma unroll
            for (int n = 0; n < 2; ++n) {
                float dk = acck[m][n][j];
                float dg = accg[m][n][j];
                float s = (dk + 1.0f + EPS_F) * __builtin_amdgcn_rcpf(dg + 1.0f + EPS_F);
                if (r0 + lrow == c0 + wc * 32 + n * 16 + lr) s = NEG_DIAG_F;
                if (F16) s = (float)(_Float16)s;   // quantize so P-max matches stored s
                acck[m][n][j] = s;
            }
        }

    // row maxes -> lmax[0..63]
#pragma unroll
    for (int m = 0; m < 2; ++m)
#pragma unroll
        for (int j = 0; j < 4; ++j) {
            float pm = fmaxf(acck[m][0][j], acck[m][1][j]);
#pragma unroll
            for (int off = 1; off < 16; off <<= 1)
                pm = fmaxf(pm, __shfl_xor(pm, off, 64));
            if (lr == 0) atomicMax(&lmax[wr * 32 + m * 16 + lg * 4 + j], __float_as_int(pm));
        }
    // col maxes -> lmax[64..127]
#pragma unroll
    for (int n = 0; n < 2; ++n) {
        float cm = acck[0][n][0];
#pragma unroll
        for (int m = 0; m < 2; ++m)
#pragma unroll
            for (int j = 0; j < 4; ++j) cm = fmaxf(cm, acck[m][n][j]);
        cm = fmaxf(cm, __shfl_xor(cm, 16, 64));
        cm = fmaxf(cm, __shfl_xor(cm, 32, 64));
        if (lg == 0) atomicMax(&lmax[64 + wc * 32 + n * 16 + lr], __float_as_int(cm));
    }

    // direct tile: bounce [row][col] then coalesced row stores
#pragma unroll
    for (int m = 0; m < 2; ++m)
#pragma unroll
        for (int n = 0; n < 2; ++n)
#pragma unroll
            for (int j = 0; j < 4; ++j)
                bnc[(wr * 32 + m * 16 + lg * 4 + j) * 66 + wc * 32 + n * 16 + lr] = acck[m][n][j];
    __syncthreads();

#pragma unroll
    for (int i = 0; i < 4; ++i) {
        int rr = i * 16 + (t >> 4);
        f32x4 v = *(const f32x4*)&bnc[rr * 66 + (t & 15) * 4];
        if (F16) {
            h16x4 hv = {(_Float16)v[0], (_Float16)v[1], (_Float16)v[2], (_Float16)v[3]};
            *(h16x4*)((_Float16*)sout + (size_t)(r0 + rr) * N + c0 + (t & 15) * 4) = hv;
        } else {
            *(f32x4*)((float*)sout + (size_t)(r0 + rr) * N + c0 + (t & 15) * 4) = v;
        }
    }
    if (t < 64) {
        P[(size_t)(r0 + t) * NPART + bx] = __int_as_float(lmax[t]);
    } else if (t < 128 && bx > by) {
        P[(size_t)(c0 + t - 64) * NPART + 64 + by] = __int_as_float(lmax[t]);
    }

    if (bx > by) {
        __syncthreads();
#pragma unroll
        for (int m = 0; m < 2; ++m)
#pragma unroll
            for (int n = 0; n < 2; ++n)
#pragma unroll
                for (int j = 0; j < 4; ++j)
                    bnc[(wc * 32 + n * 16 + lr) * 66 + wr * 32 + m * 16 + lg * 4 + j] = acck[m][n][j];
        __syncthreads();
#pragma unroll
        for (int i = 0; i < 4; ++i) {
            int rr = i * 16 + (t >> 4);
            f32x4 v = *(const f32x4*)&bnc[rr * 66 + (t & 15) * 4];
            if (F16) {
                h16x4 hv = {(_Float16)v[0], (_Float16)v[1], (_Float16)v[2], (_Float16)v[3]};
                *(h16x4*)((_Float16*)sout + (size_t)(c0 + rr) * N + r0 + (t & 15) * 4) = hv;
            } else {
                *(f32x4*)((float*)sout + (size_t)(c0 + rr) * N + r0 + (t & 15) * 4) = v;
            }
        }
    }
}

// ---------------------------------------------------------------------------
// Kernel 3a (fp16 path): out = exp(sbuf - rowmax), streaming full rows.
// ---------------------------------------------------------------------------
__global__ void finalize_f16_kernel(const _Float16* __restrict__ sbuf, float* __restrict__ out,
                                    const float* __restrict__ P, int N) {
    int row = blockIdx.x;
    int t = threadIdx.x;            // 256
    int j = t & 63;
    float m = fmaxf(P[(size_t)row * NPART + j], P[(size_t)row * NPART + 64 + j]);
#pragma unroll
    for (int off = 1; off < 64; off <<= 1)
        m = fmaxf(m, __shfl_xor(m, off, 64));
    const h16x8* s8 = (const h16x8*)(sbuf + (size_t)row * N);
    float4* o4 = (float4*)(out + (size_t)row * N);
    int n8 = N >> 3;
    for (int i = t; i < n8; i += 256) {
        h16x8 hv = s8[i];
        float4 a, b;
        a.x = __expf((float)hv[0] - m); a.y = __expf((float)hv[1] - m);
        a.z = __expf((float)hv[2] - m); a.w = __expf((float)hv[3] - m);
        b.x = __expf((float)hv[4] - m); b.y = __expf((float)hv[5] - m);
        b.z = __expf((float)hv[6] - m); b.w = __expf((float)hv[7] - m);
        o4[i * 2] = a;
        o4[i * 2 + 1] = b;
    }
}

// ---------------------------------------------------------------------------
// Kernel 3b (f32 fallback): in-place exp on out (R7).
// ---------------------------------------------------------------------------
__global__ void finalize_f32_kernel(float* __restrict__ out, const float* __restrict__ P, int N) {
    int row = blockIdx.x;
    int t = threadIdx.x;
    int j = t & 63;
    float m = fmaxf(P[(size_t)row * NPART + j], P[(size_t)row * NPART + 64 + j]);
#pragma unroll
    for (int off = 1; off < 64; off <<= 1)
        m = fmaxf(m, __shfl_xor(m, off, 64));
    float4* o4 = (float4*)(out + (size_t)row * N);
    int n4 = N >> 2;
    for (int i = t; i < n4; i += 256) {
        float4 v = o4[i];
        v.x = __expf(v.x - m);
        v.y = __expf(v.y - m);
        v.z = __expf(v.z - m);
        v.w = __expf(v.w - m);
        o4[i] = v;
    }
}

// ---------------------------------------------------------------------------
extern "C" void kernel_launch(void* const* d_in, const int* in_sizes, int n_in,
                              void* d_out, int out_size, void* d_ws, size_t ws_size,
                              hipStream_t stream) {
    const float* fk = (const float*)d_in[1];
    const float* fg = (const float*)d_in[2];
    float* out = (float*)d_out;

    int N = (int)llround(sqrt((double)out_size));   // 4096
    int D = in_sizes[1] / N;                        // 256

    char* ws = (char*)d_ws;
    size_t offP = 0;
    size_t offF = offP + (size_t)N * NPART * 4;          // P: 2 MB
    size_t offS = offF + (size_t)N * D * 4;              // fkb+fgb: 4 MB
    size_t needF16 = offS + (size_t)N * N * 2;           // sbuf: 32 MB

    float* P = (float*)(ws + offP);
    __hip_bfloat16* fkb = (__hip_bfloat16*)(ws + offF);
    __hip_bfloat16* fgb = fkb + (size_t)N * D;

    norm_cast_kernel<<<N, D, 0, stream>>>(fk, fg, fkb, fgb, P, N, D);

    dim3 grid(N / 64, N / 64);
    if (ws_size >= needF16) {
        _Float16* sbuf = (_Float16*)(ws + offS);
        gram64_kernel<1><<<grid, 256, 0, stream>>>(fkb, fgb, (void*)sbuf, P, N, D);
        finalize_f16_kernel<<<N, 256, 0, stream>>>(sbuf, out, P, N);
    } else {
        gram64_kernel<0><<<grid, 256, 0, stream>>>(fkb, fgb, (void*)out, P, N, D);
        finalize_f32_kernel<<<N, 256, 0, stream>>>(out, P, N);
    }
}